// Round 12
// baseline (623.171 us; speedup 1.0000x reference)
//
#include <hip/hip_runtime.h>
#include <hip/hip_bf16.h>
#include <stdint.h>

typedef unsigned short u16;
typedef float f32x4 __attribute__((ext_vector_type(4)));
typedef __bf16 b16x8 __attribute__((ext_vector_type(8)));
typedef u16 u16x8 __attribute__((ext_vector_type(8)));

static __device__ __forceinline__ u16 f2b(float f) {
  __hip_bfloat16 h = __float2bfloat16(f);
  return __builtin_bit_cast(u16, h);
}

static __device__ __forceinline__ void gload16(const void* g, void* l) {
  auto gp = reinterpret_cast<const __attribute__((address_space(1))) void*>(
      reinterpret_cast<uintptr_t>(g));
  auto lp = reinterpret_cast<__attribute__((address_space(3))) void*>(
      reinterpret_cast<uintptr_t>(l));
  __builtin_amdgcn_global_load_lds(gp, lp, 16, 0, 0);
}

// ---------------- fp32 -> bf16 bulk convert (8 elems/thread) ----------------
__global__ __launch_bounds__(256) void cvt_kernel(const float* __restrict__ src,
                                                  u16* __restrict__ dst, int n) {
  int i = blockIdx.x * 256 + threadIdx.x;
  const f32x4* s4 = reinterpret_cast<const f32x4*>(src);
  f32x4 a = s4[2 * i];
  f32x4 b = s4[2 * i + 1];
  u16x8 o;
  o[0] = f2b(a[0]); o[1] = f2b(a[1]); o[2] = f2b(a[2]); o[3] = f2b(a[3]);
  o[4] = f2b(b[0]); o[5] = f2b(b[1]); o[6] = f2b(b[2]); o[7] = f2b(b[3]);
  *reinterpret_cast<u16x8*>(dst + (size_t)i * 8) = o;
}

// ------------- fp32 (K x N) -> bf16 transposed (N x K) ----------------------
__global__ __launch_bounds__(256) void tcvt(const float* __restrict__ src,
                                            u16* __restrict__ dst, int K, int N) {
  __shared__ float tile[32][33];
  const int n0 = blockIdx.x * 32, k0 = blockIdx.y * 32;
  const int tx = threadIdx.x, ty = threadIdx.y;
#pragma unroll
  for (int rr = 0; rr < 4; ++rr) {
    int r = ty + rr * 8;
    tile[r][tx] = src[(size_t)(k0 + r) * N + n0 + tx];
  }
  __syncthreads();
#pragma unroll
  for (int rr = 0; rr < 4; ++rr) {
    int cc = ty + rr * 8;
    dst[(size_t)(n0 + cc) * K + k0 + tx] = f2b(tile[tx][cc]);
  }
}

// ------------- bf16 (R x C) -> bf16 transposed (C x R) ----------------------
__global__ __launch_bounds__(256) void tp16(const u16* __restrict__ src,
                                            u16* __restrict__ dst, int R, int C) {
  __shared__ u16 tile[32][33];
  const int c0 = blockIdx.x * 32, r0 = blockIdx.y * 32;
  const int tx = threadIdx.x, ty = threadIdx.y;
#pragma unroll
  for (int rr = 0; rr < 4; ++rr) {
    int r = ty + rr * 8;
    tile[r][tx] = src[(size_t)(r0 + r) * C + c0 + tx];
  }
  __syncthreads();
#pragma unroll
  for (int rr = 0; rr < 4; ++rr) {
    int cc = ty + rr * 8;
    dst[(size_t)(c0 + cc) * R + r0 + tx] = tile[tx][cc];
  }
}

// ------------- GEMM: C(MxN) = A(MxK,bf16) * Bt(NxK,bf16)^T ------------------
// 128x128 tile, BK=64, 4 waves (2x2), 16x16x32 bf16 MFMA, global_load_lds.
template <typename OT, bool BIAS>
__global__ __launch_bounds__(256) void gemm_bt(const u16* __restrict__ A,
                                               const u16* __restrict__ Bt,
                                               OT* __restrict__ C,
                                               const float* __restrict__ bias,
                                               int M, int N, int K, float scale) {
  __shared__ u16 lA[128 * 64];
  __shared__ u16 lB[128 * 64];
  const int tid = threadIdx.x;
  const int lane = tid & 63, wid = tid >> 6;
  const int wr = wid >> 1, wc = wid & 1;
  const int m0 = blockIdx.y * 128, n0 = blockIdx.x * 128;
  const int l15 = lane & 15, l4 = lane >> 4;

  f32x4 acc[4][4];
#pragma unroll
  for (int i = 0; i < 4; ++i)
#pragma unroll
    for (int j = 0; j < 4; ++j) acc[i][j] = f32x4{0.f, 0.f, 0.f, 0.f};

  for (int kt = 0; kt < K; kt += 64) {
#pragma unroll
    for (int i = 0; i < 4; ++i) {
      const int cb = i * 256 + wid * 64;       // wave-uniform chunk base
      const int c = cb + lane;                 // per-lane chunk (16B each)
      const int row = c >> 3, k8 = (c & 7) << 3;
      gload16(A + (size_t)(m0 + row) * K + kt + k8, &lA[cb * 8]);
      gload16(Bt + (size_t)(n0 + row) * K + kt + k8, &lB[cb * 8]);
    }
    __syncthreads();
#pragma unroll
    for (int kk = 0; kk < 64; kk += 32) {
      b16x8 af[4], bf[4];
#pragma unroll
      for (int mi = 0; mi < 4; ++mi)
        af[mi] = *reinterpret_cast<const b16x8*>(
            &lA[(wr * 64 + mi * 16 + l15) * 64 + kk + l4 * 8]);
#pragma unroll
      for (int ni = 0; ni < 4; ++ni)
        bf[ni] = *reinterpret_cast<const b16x8*>(
            &lB[(wc * 64 + ni * 16 + l15) * 64 + kk + l4 * 8]);
#pragma unroll
      for (int mi = 0; mi < 4; ++mi)
#pragma unroll
        for (int ni = 0; ni < 4; ++ni)
          acc[mi][ni] = __builtin_amdgcn_mfma_f32_16x16x32_bf16(
              af[mi], bf[ni], acc[mi][ni], 0, 0, 0);
    }
    __syncthreads();
  }

#pragma unroll
  for (int mi = 0; mi < 4; ++mi) {
#pragma unroll
    for (int ni = 0; ni < 4; ++ni) {
      const int col = n0 + wc * 64 + ni * 16 + l15;
      float bb = 0.f;
      if constexpr (BIAS) bb = bias[col];
#pragma unroll
      for (int r = 0; r < 4; ++r) {
        const int row = m0 + wr * 64 + mi * 16 + l4 * 4 + r;
        float v = acc[mi][ni][r] * scale + bb;
        if constexpr (sizeof(OT) == 2) {
          C[(size_t)row * N + col] = f2b(v);
        } else {
          C[(size_t)row * N + col] = v;
        }
      }
    }
  }
}

// ------------- flash attention, GQA + sliding window ------------------------
// Q: [T][2048] bf16 pre-scaled by 1/sqrt(128); Kb: [T][512]; Vt: [512][T];
// att out: [T][2048] bf16. Block = 4 waves; wave handles 16 q-rows of head h.
__global__ __launch_bounds__(256) void attn_kernel(const u16* __restrict__ Q,
                                                   const u16* __restrict__ Kb,
                                                   const u16* __restrict__ Vt,
                                                   u16* __restrict__ att) {
  const int h = blockIdx.y;
  const int g = h >> 2;  // 4 q-heads per kv group
  const int lane = threadIdx.x & 63, wid = threadIdx.x >> 6;
  const int q0 = blockIdx.x * 64 + wid * 16;
  const int l15 = lane & 15, l4 = lane >> 4;
  __shared__ u16 pl[4][16 * 40];  // per-wave P tile, row stride 40 (pad)

  b16x8 qf[4];
  {
    const u16* qp = Q + (size_t)(q0 + l15) * 2048 + h * 128 + l4 * 8;
#pragma unroll
    for (int dc = 0; dc < 4; ++dc)
      qf[dc] = *reinterpret_cast<const b16x8*>(qp + dc * 32);
  }

  f32x4 oacc[8];
#pragma unroll
  for (int i = 0; i < 8; ++i) oacc[i] = f32x4{0.f, 0.f, 0.f, 0.f};
  float mrow[4] = {-1e30f, -1e30f, -1e30f, -1e30f};
  float lrow[4] = {0.f, 0.f, 0.f, 0.f};

  const int s_lo = (q0 > 1023) ? ((q0 - 1023) & ~31) : 0;
  const int s_hi = q0 + 15;

  for (int s0 = s_lo; s0 <= s_hi; s0 += 32) {
    // ---- S = Q K^T (16q x 32k), two 16-key halves
    f32x4 sf[2] = {f32x4{0.f, 0.f, 0.f, 0.f}, f32x4{0.f, 0.f, 0.f, 0.f}};
#pragma unroll
    for (int half = 0; half < 2; ++half) {
      const u16* kp = Kb + (size_t)(s0 + half * 16 + l15) * 512 + g * 128 + l4 * 8;
#pragma unroll
      for (int dc = 0; dc < 4; ++dc)
        sf[half] = __builtin_amdgcn_mfma_f32_16x16x32_bf16(
            qf[dc], *reinterpret_cast<const b16x8*>(kp + dc * 32), sf[half], 0, 0, 0);
    }
    // ---- mask (causal + window)
    float pm[4];
#pragma unroll
    for (int r = 0; r < 4; ++r) {
      const int qi = q0 + l4 * 4 + r;
#pragma unroll
      for (int half = 0; half < 2; ++half) {
        const int kj = s0 + half * 16 + l15;
        const bool ok = (kj <= qi) && (qi - kj < 1024);
        if (!ok) sf[half][r] = -1e30f;
      }
      pm[r] = fmaxf(sf[0][r], sf[1][r]);
    }
#pragma unroll
    for (int off = 8; off; off >>= 1)
#pragma unroll
      for (int r = 0; r < 4; ++r) pm[r] = fmaxf(pm[r], __shfl_xor(pm[r], off));

    // ---- online softmax update
    float cs[4], rs[4], p0[4], p1[4];
#pragma unroll
    for (int r = 0; r < 4; ++r) {
      const float mnew = fmaxf(mrow[r], pm[r]);
      cs[r] = __expf(mrow[r] - mnew);
      const float pv = (mnew > -1e29f) ? 1.f : 0.f;  // no valid key yet -> zero
      mrow[r] = mnew;
      p0[r] = __expf(sf[0][r] - mnew) * pv;
      p1[r] = __expf(sf[1][r] - mnew) * pv;
      rs[r] = p0[r] + p1[r];
    }
#pragma unroll
    for (int off = 8; off; off >>= 1)
#pragma unroll
      for (int r = 0; r < 4; ++r) rs[r] += __shfl_xor(rs[r], off);
#pragma unroll
    for (int r = 0; r < 4; ++r) lrow[r] = lrow[r] * cs[r] + rs[r];
#pragma unroll
    for (int dc = 0; dc < 8; ++dc)
#pragma unroll
      for (int r = 0; r < 4; ++r) oacc[dc][r] *= cs[r];

    // ---- P: C-layout -> A-layout via padded LDS tile
    u16* pw = &pl[wid][0];
#pragma unroll
    for (int r = 0; r < 4; ++r) {
      const int prow = l4 * 4 + r;
      pw[prow * 40 + l15] = f2b(p0[r]);
      pw[prow * 40 + 16 + l15] = f2b(p1[r]);
    }
    asm volatile("s_waitcnt lgkmcnt(0)" ::: "memory");
    const b16x8 pf = *reinterpret_cast<const b16x8*>(&pw[l15 * 40 + l4 * 8]);

    // ---- O += P V  (8 d-chunks of 16)
#pragma unroll
    for (int dc = 0; dc < 8; ++dc) {
      const u16* vp = Vt + (size_t)(g * 128 + dc * 16 + l15) * 4096 + s0 + l4 * 8;
      oacc[dc] = __builtin_amdgcn_mfma_f32_16x16x32_bf16(
          pf, *reinterpret_cast<const b16x8*>(vp), oacc[dc], 0, 0, 0);
    }
  }

  // ---- epilogue: normalize + store bf16
#pragma unroll
  for (int dc = 0; dc < 8; ++dc) {
#pragma unroll
    for (int r = 0; r < 4; ++r) {
      const float o = oacc[dc][r] / lrow[r];
      att[(size_t)(q0 + l4 * 4 + r) * 2048 + h * 128 + dc * 16 + l15] = f2b(o);
    }
  }
}

// ---------------------------------------------------------------------------
extern "C" void kernel_launch(void* const* d_in, const int* in_sizes, int n_in,
                              void* d_out, int out_size, void* d_ws, size_t ws_size,
                              hipStream_t stream) {
  const float* x  = (const float*)d_in[0];
  const float* Wq = (const float*)d_in[1];
  const float* Wk = (const float*)d_in[2];
  const float* Wv = (const float*)d_in[3];
  const float* Wo = (const float*)d_in[4];
  const float* bo = (const float*)d_in[5];
  float* out = (float*)d_out;

  // ---- workspace layout (u16 elements), 36 MiB total in d_ws ----
  // Buffers that must survive until the final GEMM live in d_ws; buffers
  // dead before the final GEMM (Qb/Kb/Vb/Vt, 28 MiB) live in d_out scratch
  // (32 MiB, re-poisoned each launch, fully overwritten by the final GEMM).
  u16* ws  = (u16*)d_ws;
  u16* xb  = ws;                   // 4096*2048 = 8388608
  u16* Wqt = xb + 8388608;         // 2048*2048 = 4194304
  u16* Wot = Wqt + 4194304;        // 4194304
  u16* Wkt = Wot + 4194304;        // 512*2048  = 1048576
  u16* Wvt = Wkt + 1048576;        // 1048576   -> ws total 18874368 u16 = 36 MiB
  u16* att = xb;                   // alias: xb dead after V GEMM

  u16* os  = (u16*)d_out;          // scratch region, 16777216 u16 capacity
  u16* Qb  = os;                   // 8388608
  u16* Kb  = Qb + 8388608;         // 2097152
  u16* Vb  = Kb + 2097152;         // 2097152
  u16* Vt  = Vb + 2097152;         // 2097152  -> 14680064 u16 = 28 MiB <= 32 MiB

  const dim3 tb(32, 8);

  cvt_kernel<<<4096, 256, 0, stream>>>(x, xb, 8388608);
  tcvt<<<dim3(64, 64), tb, 0, stream>>>(Wq, Wqt, 2048, 2048);
  tcvt<<<dim3(16, 64), tb, 0, stream>>>(Wk, Wkt, 2048, 512);
  tcvt<<<dim3(16, 64), tb, 0, stream>>>(Wv, Wvt, 2048, 512);
  tcvt<<<dim3(64, 64), tb, 0, stream>>>(Wo, Wot, 2048, 2048);

  // Q = x Wq * (1/sqrt(128));  K = x Wk;  V = x Wv
  gemm_bt<u16, false><<<dim3(16, 32), 256, 0, stream>>>(
      xb, Wqt, Qb, nullptr, 4096, 2048, 2048, 0.08838834764831845f);
  gemm_bt<u16, false><<<dim3(4, 32), 256, 0, stream>>>(
      xb, Wkt, Kb, nullptr, 4096, 512, 2048, 1.f);
  gemm_bt<u16, false><<<dim3(4, 32), 256, 0, stream>>>(
      xb, Wvt, Vb, nullptr, 4096, 512, 2048, 1.f);

  tp16<<<dim3(16, 128), tb, 0, stream>>>(Vb, Vt, 4096, 512);

  attn_kernel<<<dim3(64, 16), 256, 0, stream>>>(Qb, Kb, Vt, att);

  // out = att Wo + bo   (fp32 out).  Reads att/Wot (d_ws), writes d_out;
  // the d_out scratch buffers are all dead by this point.
  gemm_bt<float, true><<<dim3(16, 32), 256, 0, stream>>>(
      att, Wot, out, bo, 4096, 2048, 2048, 1.f);
}